// Round 2
// baseline (523.183 us; speedup 1.0000x reference)
//
#include <hip/hip_runtime.h>

#define NBINS 15
#define TPB   256
#define GRID  2048
#define NROWS (3 * NBINS)          // rows: [0,15)=count, [15,30)=conf, [30,45)=acc
#define HCOLS 64                   // one column per lane-id: wave-private addresses
#define HSIZE (NROWS * HCOLS)      // 2880 floats = 11520 B LDS -> 8 blocks/CU, 100% occ

// ---------------------------------------------------------------------------
// O(1) binning + native LDS float atomics (asm-guaranteed ds_add_f32).
// Bin predicate is IDENTICAL to the verified kernels: bin b = { c : c >
// b*(1/15.0f) && !(c > (b+1)*(1/15.0f)) }; b0 = trunc(c*15) corrected by one
// exact up/down check against the same boundary formula (refcheck-verified in
// the previous round). Invalid c (<=0 or >1) adds 0.0f to bin 0 (harmless).
//
// Address layout: addr = hist_base + (tid&63)*4 + b*HCOLS*4. All 64 lanes of
// a wave use DISTINCT addresses (col==lane) -> no same-address contention,
// 2-way bank alias only (free). The three tables are reached from ONE address
// register via 16-bit immediate offsets (0 / 3840 / 7680).
__device__ __forceinline__ void ece_elem(float c, float a, unsigned hcol) {
    const float INV15 = 1.0f / 15.0f;
    float t  = c * 15.0f;
    float f0 = truncf(t);                         // integer-valued, exact
    int   b  = (int)f0;
    b += (c > (f0 + 1.0f) * INV15) ? 1 : 0;       // exact predicate vs bound(b0+1)
    b -= (c <= f0 * INV15)         ? 1 : 0;       // exact predicate vs bound(b0)
    b = min(max(b, 0), NBINS - 1);
    bool valid = (c > 0.0f) && (c <= 1.0f);
    float w  = valid ? 1.0f : 0.0f;
    float wc = valid ? c    : 0.0f;
    float wa = valid ? a    : 0.0f;
    unsigned addr = hcol + ((unsigned)b << 8);    // b * HCOLS * 4
    asm volatile("ds_add_f32 %0, %1\n\t"
                 "ds_add_f32 %0, %2 offset:3840\n\t"   // + NBINS*HCOLS*4
                 "ds_add_f32 %0, %3 offset:7680"       // + 2*NBINS*HCOLS*4
                 :: "v"(addr), "v"(w), "v"(wc), "v"(wa));
}

__global__ __launch_bounds__(TPB, 8) void ece_partial(const float* __restrict__ conf,
                                                      const float* __restrict__ acc,
                                                      float* __restrict__ ws,
                                                      int N, int slotMode) {
    __shared__ float hist[HSIZE];
    const int tid  = threadIdx.x;
    const int lane = tid & 63;
    const int wid  = tid >> 6;

    for (int i = tid; i < HSIZE; i += TPB) hist[i] = 0.0f;
    __syncthreads();

    // 32-bit LDS byte offset of this thread's private column (generic LDS
    // pointer truncates to the LDS window offset on gfx9+).
    const unsigned hcol = (unsigned)(uintptr_t)hist + ((unsigned)lane << 2);

    const int gid    = blockIdx.x * TPB + tid;
    const int stride = GRID * TPB;
    const float4* c4 = (const float4*)conf;
    const float4* a4 = (const float4*)acc;
    const int N8 = N >> 3;

    // register double-buffered main loop: next iteration's 4x dwordx4 issued
    // before processing the current 8 elements (HBM latency hides under the
    // ~150 VALU+DS ops of the batch).
    int  p    = gid;
    bool have = p < N8;
    float4 c0, c1, a0, a1;
    if (have) {
        c0 = c4[2 * p]; c1 = c4[2 * p + 1];
        a0 = a4[2 * p]; a1 = a4[2 * p + 1];
    }
    while (have) {
        const int  pn = p + stride;
        const bool hn = pn < N8;
        const int  pl = hn ? pn : p;              // clamp: always-valid prefetch addr
        float4 d0 = c4[2 * pl], d1 = c4[2 * pl + 1];
        float4 e0 = a4[2 * pl], e1 = a4[2 * pl + 1];

        ece_elem(c0.x, a0.x, hcol);
        ece_elem(c0.y, a0.y, hcol);
        ece_elem(c0.z, a0.z, hcol);
        ece_elem(c0.w, a0.w, hcol);
        ece_elem(c1.x, a1.x, hcol);
        ece_elem(c1.y, a1.y, hcol);
        ece_elem(c1.z, a1.z, hcol);
        ece_elem(c1.w, a1.w, hcol);

        c0 = d0; c1 = d1; a0 = e0; a1 = e1;
        p = pn; have = hn;
    }

    // tail (no-op for N = 2^25)
    for (int i = (N8 << 3) + gid; i < N; i += stride)
        ece_elem(conf[i], acc[i], hcol);

    __syncthreads();   // conservatively drains lgkmcnt -> all ds_adds landed

    // block reduce: wave w handles rows w, w+4, ...; HCOLS==64 -> one column
    // per lane, butterfly over 64 lanes, lane 0 publishes.
    for (int r = wid; r < NROWS; r += 4) {
        float s = hist[r * HCOLS + lane];
        #pragma unroll
        for (int sft = 32; sft >= 1; sft >>= 1) s += __shfl_xor(s, sft);
        if (lane == 0) {
            if (slotMode) ws[r * GRID + blockIdx.x] = s;   // block partial, exact f32
            else          atomicAdd(&ws[r], s);
        }
    }
}

// ---------------------------------------------------------------------------
// Slot-mode final: reduce 45 rows x GRID columns in f64, then ECE.
__global__ __launch_bounds__(1024) void ece_final_slots(const float* __restrict__ ws,
                                                        float* __restrict__ out, int N) {
    __shared__ double red[NROWS];
    const int tid = threadIdx.x, lane = tid & 63, w = tid >> 6;
    for (int r = w; r < NROWS; r += 16) {
        double s = 0.0;
        #pragma unroll 4
        for (int it = 0; it < GRID / 64; ++it)
            s += (double)ws[r * GRID + it * 64 + lane];
        #pragma unroll
        for (int sft = 32; sft >= 1; sft >>= 1) s += __shfl_xor(s, sft);
        if (lane == 0) red[r] = s;
    }
    __syncthreads();
    if (w == 0) {
        double per = 0.0;
        if (lane < NBINS) {
            double cnt = red[lane];
            double cs  = red[NBINS + lane];
            double as  = red[2 * NBINS + lane];
            double safe = cnt > 1.0 ? cnt : 1.0;
            double d = cs / safe - as / safe;
            per = (cnt > 0.0) ? d * d * (cnt / (double)N) : 0.0;
        }
        per += __shfl_down(per, 8);
        per += __shfl_down(per, 4);
        per += __shfl_down(per, 2);
        per += __shfl_down(per, 1);
        if (lane == 0) out[0] = (float)per;
    }
}

// ---------------------------------------------------------------------------
// Atomic-mode fallback (tiny ws): zero + atomic partials + tiny final.
__global__ void ece_zero_ws(float* __restrict__ ws) {
    int t = threadIdx.x;
    if (t < NROWS) ws[t] = 0.0f;
}

__global__ void ece_final_atomic(const float* __restrict__ ws,
                                 float* __restrict__ out, int N) {
    int lane = threadIdx.x;
    double per = 0.0;
    if (lane < NBINS) {
        double cnt = (double)ws[lane];
        double cs  = (double)ws[NBINS + lane];
        double as  = (double)ws[2 * NBINS + lane];
        double safe = cnt > 1.0 ? cnt : 1.0;
        double d = cs / safe - as / safe;
        per = (cnt > 0.0) ? d * d * (cnt / (double)N) : 0.0;
    }
    per += __shfl_down(per, 8);
    per += __shfl_down(per, 4);
    per += __shfl_down(per, 2);
    per += __shfl_down(per, 1);
    if (lane == 0) out[0] = (float)per;
}

// ---------------------------------------------------------------------------
extern "C" void kernel_launch(void* const* d_in, const int* in_sizes, int n_in,
                              void* d_out, int out_size, void* d_ws, size_t ws_size,
                              hipStream_t stream) {
    const float* conf = (const float*)d_in[0];
    const float* acc  = (const float*)d_in[1];
    float* out = (float*)d_out;
    float* ws  = (float*)d_ws;
    const int N = in_sizes[0];

    const size_t need = (size_t)NROWS * GRID * sizeof(float);
    const int slotMode = (ws_size >= need) ? 1 : 0;

    if (!slotMode) ece_zero_ws<<<1, 64, 0, stream>>>(ws);
    ece_partial<<<GRID, TPB, 0, stream>>>(conf, acc, ws, N, slotMode);
    if (slotMode) ece_final_slots<<<1, 1024, 0, stream>>>(ws, out, N);
    else          ece_final_atomic<<<1, 64, 0, stream>>>(ws, out, N);
}

// Round 3
// 63.567 us; speedup vs baseline: 8.2305x; 8.2305x over previous
//
#include <hip/hip_runtime.h>

#define NBINS 15
#define TPB   128
#define GRID  1280                 // 256 CU x 5 blocks/CU (LDS-bound) = one generation
#define NROWS (3 * NBINS)          // ws rows: [0,15)=count, [15,30)=conf, [30,45)=acc
#define HREC  (NBINS * TPB)        // float4 records: [bin][tid] -> 30720 B LDS

// ---------------------------------------------------------------------------
// O(1) binning + per-thread-private LDS float4 RMW (no atomics!).
// R2 post-mortem: ds_add_f32 is ~204 cyc/wave-op (per-lane serialized) -> LDS
// atomics are unusable. Plain ds_read_b128/ds_write_b128 run at ~12 cyc/wave.
// Record layout [bin][tid] x float4(count, sum_c, sum_a, pad): every lane owns
// a distinct 16B slot; bin stride = TPB*16 B = 2048 B == 0 mod 128 -> bank
// pattern independent of bin; lanes 0..7 cover all 32 banks -> conflict-free.
// Thread-private columns -> RMW needs no atomicity; DS pipe is in-order per
// wave -> write[i] -> read[i+1] to same addr is safe without waits.
//
// Bin predicate is IDENTICAL to the refcheck-verified kernels: bin b =
// { c : c > b*(1/15.0f) && !(c > (b+1)*(1/15.0f)) }; b0 = trunc(c*15)
// corrected by one exact up/down check against the same boundary formula.
// Invalid c (<=0 or >1): w=0 -> adds 0.0f (harmless).
__device__ __forceinline__ void ece_elem(float c, float a,
                                         float4* __restrict__ slot) {
    const float INV15 = 1.0f / 15.0f;
    float t  = c * 15.0f;
    float f0 = truncf(t);                         // integer-valued, exact
    int   b  = (int)f0;
    b += (c > (f0 + 1.0f) * INV15) ? 1 : 0;       // exact predicate vs bound(b0+1)
    b -= (c <= f0 * INV15)         ? 1 : 0;       // exact predicate vs bound(b0)
    b = min(max(b, 0), NBINS - 1);
    float w = ((c > 0.0f) && (c <= 1.0f)) ? 1.0f : 0.0f;
    float4 r = slot[b * TPB];                     // ds_read_b128
    r.x += w;
    r.y = fmaf(w, c, r.y);
    r.z = fmaf(w, a, r.z);
    slot[b * TPB] = r;                            // ds_write_b128
}

__global__ __launch_bounds__(TPB, 2) void ece_partial(const float* __restrict__ conf,
                                                      const float* __restrict__ acc,
                                                      float* __restrict__ ws,
                                                      int N, int slotMode) {
    __shared__ float4 hist4[HREC];
    __shared__ float  wred[2][NROWS];
    const int tid  = threadIdx.x;
    const int lane = tid & 63;
    const int wid  = tid >> 6;

    {   // zero-init (float4 stores)
        float4 z = {0.f, 0.f, 0.f, 0.f};
        for (int i = tid; i < HREC; i += TPB) hist4[i] = z;
    }
    __syncthreads();

    float4* slot = &hist4[tid];                   // this thread's private column

    const int gid    = blockIdx.x * TPB + tid;
    const int stride = GRID * TPB;
    const float4* c4 = (const float4*)conf;
    const float4* a4 = (const float4*)acc;
    const int N8 = N >> 3;

    // register double-buffered main loop: next iteration's 4x dwordx4 issued
    // before processing the current 8 elements (HBM latency hides under the
    // ~8x(17 VALU + 2 DS) ops of the batch + 10 interleaved waves/CU).
    int  p    = gid;
    bool have = p < N8;
    float4 c0, c1, a0, a1;
    if (have) {
        c0 = c4[2 * p]; c1 = c4[2 * p + 1];
        a0 = a4[2 * p]; a1 = a4[2 * p + 1];
    }
    while (have) {
        const int  pn = p + stride;
        const bool hn = pn < N8;
        const int  pl = hn ? pn : p;              // clamp: always-valid prefetch addr
        float4 d0 = c4[2 * pl], d1 = c4[2 * pl + 1];
        float4 e0 = a4[2 * pl], e1 = a4[2 * pl + 1];

        ece_elem(c0.x, a0.x, slot);
        ece_elem(c0.y, a0.y, slot);
        ece_elem(c0.z, a0.z, slot);
        ece_elem(c0.w, a0.w, slot);
        ece_elem(c1.x, a1.x, slot);
        ece_elem(c1.y, a1.y, slot);
        ece_elem(c1.z, a1.z, slot);
        ece_elem(c1.w, a1.w, slot);

        c0 = d0; c1 = d1; a0 = e0; a1 = e1;
        p = pn; have = hn;
    }

    // tail (no-op for N = 2^25); no wave-uniformity requirement
    for (int i = (N8 << 3) + gid; i < N; i += stride)
        ece_elem(conf[i], acc[i], slot);

    __syncthreads();

    // block reduce: for each bin, butterfly the 128 thread-columns.
    for (int b = 0; b < NBINS; ++b) {
        float4 r = hist4[b * TPB + tid];
        float x = r.x, y = r.y, z = r.z;
        #pragma unroll
        for (int s = 32; s >= 1; s >>= 1) {
            x += __shfl_xor(x, s);
            y += __shfl_xor(y, s);
            z += __shfl_xor(z, s);
        }
        if (lane == 0) {
            wred[wid][b]             = x;
            wred[wid][NBINS + b]     = y;
            wred[wid][2 * NBINS + b] = z;
        }
    }
    __syncthreads();

    if (tid < NROWS) {
        float S = wred[0][tid] + wred[1][tid];
        if (slotMode) ws[tid * GRID + blockIdx.x] = S;   // block partial, f32
        else          atomicAdd(&ws[tid], S);
    }
}

// ---------------------------------------------------------------------------
// Slot-mode final: reduce 45 rows x GRID columns in f64, then ECE.
__global__ __launch_bounds__(1024) void ece_final_slots(const float* __restrict__ ws,
                                                        float* __restrict__ out, int N) {
    __shared__ double red[NROWS];
    const int tid = threadIdx.x, lane = tid & 63, w = tid >> 6;
    for (int r = w; r < NROWS; r += 16) {
        double s = 0.0;
        #pragma unroll 4
        for (int it = 0; it < GRID / 64; ++it)
            s += (double)ws[r * GRID + it * 64 + lane];
        #pragma unroll
        for (int sft = 32; sft >= 1; sft >>= 1) s += __shfl_xor(s, sft);
        if (lane == 0) red[r] = s;
    }
    __syncthreads();
    if (w == 0) {
        double per = 0.0;
        if (lane < NBINS) {
            double cnt = red[lane];
            double cs  = red[NBINS + lane];
            double as  = red[2 * NBINS + lane];
            double safe = cnt > 1.0 ? cnt : 1.0;
            double d = cs / safe - as / safe;
            per = (cnt > 0.0) ? d * d * (cnt / (double)N) : 0.0;
        }
        per += __shfl_down(per, 8);
        per += __shfl_down(per, 4);
        per += __shfl_down(per, 2);
        per += __shfl_down(per, 1);
        if (lane == 0) out[0] = (float)per;
    }
}

// ---------------------------------------------------------------------------
// Atomic-mode fallback (tiny ws): zero + atomic partials + tiny final.
__global__ void ece_zero_ws(float* __restrict__ ws) {
    int t = threadIdx.x;
    if (t < NROWS) ws[t] = 0.0f;
}

__global__ void ece_final_atomic(const float* __restrict__ ws,
                                 float* __restrict__ out, int N) {
    int lane = threadIdx.x;
    double per = 0.0;
    if (lane < NBINS) {
        double cnt = (double)ws[lane];
        double cs  = (double)ws[NBINS + lane];
        double as  = (double)ws[2 * NBINS + lane];
        double safe = cnt > 1.0 ? cnt : 1.0;
        double d = cs / safe - as / safe;
        per = (cnt > 0.0) ? d * d * (cnt / (double)N) : 0.0;
    }
    per += __shfl_down(per, 8);
    per += __shfl_down(per, 4);
    per += __shfl_down(per, 2);
    per += __shfl_down(per, 1);
    if (lane == 0) out[0] = (float)per;
}

// ---------------------------------------------------------------------------
extern "C" void kernel_launch(void* const* d_in, const int* in_sizes, int n_in,
                              void* d_out, int out_size, void* d_ws, size_t ws_size,
                              hipStream_t stream) {
    const float* conf = (const float*)d_in[0];
    const float* acc  = (const float*)d_in[1];
    float* out = (float*)d_out;
    float* ws  = (float*)d_ws;
    const int N = in_sizes[0];

    const size_t need = (size_t)NROWS * GRID * sizeof(float);
    const int slotMode = (ws_size >= need) ? 1 : 0;

    if (!slotMode) ece_zero_ws<<<1, 64, 0, stream>>>(ws);
    ece_partial<<<GRID, TPB, 0, stream>>>(conf, acc, ws, N, slotMode);
    if (slotMode) ece_final_slots<<<1, 1024, 0, stream>>>(ws, out, N);
    else          ece_final_atomic<<<1, 64, 0, stream>>>(ws, out, N);
}